// Round 3
// baseline (438.708 us; speedup 1.0000x reference)
//
#include <hip/hip_runtime.h>

// LSTMCell with attention, MI355X gfx950.
// Round 3: att GEMM fused into main GEMM (two sequential K-loops, one kernel,
// fully in-register epilogue — attprod 64MB round-trip eliminated);
// cast kernel widened to 16B stores (ushort8) with grid-stride loop.

typedef __attribute__((ext_vector_type(8))) __bf16 bf16x8;
typedef __attribute__((ext_vector_type(8))) unsigned short ushort8;
typedef __attribute__((ext_vector_type(4))) float f32x4;

#define AS1 __attribute__((address_space(1)))
#define AS3 __attribute__((address_space(3)))

__device__ __forceinline__ void gld16(const unsigned short* g, unsigned short* l) {
    __builtin_amdgcn_global_load_lds((const AS1 void*)g, (AS3 void*)l, 16, 0, 0);
}

__device__ __forceinline__ unsigned short f2bf(float f) {
    unsigned int u = __builtin_bit_cast(unsigned int, f);
    u += 0x7fffu + ((u >> 16) & 1u);   // RNE
    return (unsigned short)(u >> 16);
}

__device__ __forceinline__ float sigmoidf_(float x) { return 1.f / (1.f + __expf(-x)); }
__device__ __forceinline__ float tanhf_(float x) {
    float e = __expf(-2.f * fabsf(x));
    float t = (1.f - e) / (1.f + e);
    return x >= 0.f ? t : -t;
}

__device__ __forceinline__ bf16x8 ldfrag(const unsigned short* p) {
    return __builtin_bit_cast(bf16x8, *(const ushort8*)p);
}

// ---------------- fused cast/pack + bias kernel ----------------
// Unit of work: 8 fp32 -> 8 bf16 (two float4 reads, one 16B ushort8 store).
// Segments: input->XH[:,0:1024], hx->XH[:,1024:2048], att->ATTb,
// w_ih->W4[:,0:1024], w_hh->W4[:,1024:2048], w_att->WA.
__global__ void cast_all_k(const float* __restrict__ input, const float* __restrict__ hx,
                           const float* __restrict__ att,   const float* __restrict__ w_ih,
                           const float* __restrict__ w_hh,  const float* __restrict__ w_att,
                           const float* __restrict__ b_ih,  const float* __restrict__ b_hh,
                           unsigned short* __restrict__ XH, unsigned short* __restrict__ ATTb,
                           unsigned short* __restrict__ W4, unsigned short* __restrict__ WA,
                           float* __restrict__ bias4)
{
    int gid = blockIdx.x * blockDim.x + threadIdx.x;
    if (gid < 4096) bias4[gid] = b_ih[gid] + b_hh[gid];
    const int total = 4456448;  // total float8 units
    for (int i = gid; i < total; i += gridDim.x * blockDim.x) {
        const float* src; unsigned short* dst; int ld, off, rel;
        if (i < 1048576)      { src = input; dst = XH;   ld = 2048; off = 0;    rel = i; }
        else if (i < 2097152) { src = hx;    dst = XH;   ld = 2048; off = 1024; rel = i - 1048576; }
        else if (i < 3145728) { src = att;   dst = ATTb; ld = 1024; off = 0;    rel = i - 2097152; }
        else if (i < 3670016) { src = w_ih;  dst = W4;   ld = 2048; off = 0;    rel = i - 3145728; }
        else if (i < 4194304) { src = w_hh;  dst = W4;   ld = 2048; off = 1024; rel = i - 3670016; }
        else                  { src = w_att; dst = WA;   ld = 1024; off = 0;    rel = i - 4194304; }
        int e = rel * 8;
        int r = e >> 10, c = e & 1023;   // all sources have 1024 fp32 cols
        const float4 v0 = *(const float4*)(src + e);
        const float4 v1 = *(const float4*)(src + e + 4);
        ushort8 p;
        p[0] = f2bf(v0.x); p[1] = f2bf(v0.y); p[2] = f2bf(v0.z); p[3] = f2bf(v0.w);
        p[4] = f2bf(v1.x); p[5] = f2bf(v1.y); p[6] = f2bf(v1.z); p[7] = f2bf(v1.w);
        *(ushort8*)(dst + r * ld + off + c) = p;
    }
}

// ---------------- fused GEMM + full LSTM epilogue ----------------
// Block (bx,by): rows row0..row0+127, H-cols n0..n0+31.
// Phase 1: gates = XH[8192x2048] @ W4[4096x2048]^T  (tile rows = gate*32+j)
// Phase 2: att_gates = ATTb[8192x1024] @ WA[2048x1024]^T (tile rows = s*32+j)
// Epilogue fully in-register: cy = sig(f)*cx + sig(i)*tanh(g) + sig(ia)*tanh(ag);
// hy = sig(o)*tanh(cy).
__global__ __launch_bounds__(256, 2) void fused_gemm_k(
    const unsigned short* __restrict__ XH, const unsigned short* __restrict__ W4,
    const unsigned short* __restrict__ ATTb, const unsigned short* __restrict__ WA,
    const float* __restrict__ bias4, const float* __restrict__ bias_att,
    const float* __restrict__ cx, float* __restrict__ out)
{
    __shared__ unsigned short As[128 * 32];
    __shared__ unsigned short Bs[128 * 32];
    const int tid  = threadIdx.x;
    const int wave = tid >> 6, lane = tid & 63;
    const int l15 = lane & 15, quad = lane >> 4;
    const int row0 = blockIdx.x * 128;   // 64 blocks
    const int n0   = blockIdx.y * 32;    // 32 blocks of 32 H-cols

    const f32x4 z = {0.f, 0.f, 0.f, 0.f};
    f32x4 acc[2][8];     // gates: [row frag][gate*2 + col half]
#pragma unroll
    for (int i = 0; i < 2; ++i)
#pragma unroll
        for (int j = 0; j < 8; ++j) acc[i][j] = z;

    const int ar = tid >> 2;
    const int kp_sw = (tid & 3) ^ ((ar >> 1) & 3);
    // LDS destinations (wave-uniform base + lane*16 order: chunk index == tid)
    unsigned short* aL0 = As + tid * 8;  unsigned short* aL1 = As + (tid + 256) * 8;
    unsigned short* bL0 = Bs + tid * 8;  unsigned short* bL1 = Bs + (tid + 256) * 8;

    // fragment-read swizzle term — lane-constant
    const int sw8 = (quad ^ ((l15 >> 1) & 3)) * 8;
    const int aoff0 = (wave * 32 + l15) * 32 + sw8;
    const int aoff1 = aoff0 + 16 * 32;

    // ---- phase 1: gates GEMM, K=2048 ----
    {
        const unsigned short* aG0 = XH + (row0 + ar) * 2048 + kp_sw * 8;
        const unsigned short* aG1 = aG0 + 64 * 2048;
        const unsigned short* bG0 = W4 + ((ar >> 5) * 1024 + n0 + (ar & 31)) * 2048 + kp_sw * 8;
        const unsigned short* bG1 = bG0 + 2 * 1024 * 2048;   // tile rows +64 => gate +2
        for (int kt = 0; kt < 64; ++kt) {
            gld16(aG0, aL0); gld16(aG1, aL1);
            gld16(bG0, bL0); gld16(bG1, bL1);
            aG0 += 32; aG1 += 32; bG0 += 32; bG1 += 32;
            __syncthreads();
            bf16x8 a0 = ldfrag(As + aoff0);
            bf16x8 a1 = ldfrag(As + aoff1);
#pragma unroll
            for (int cf = 0; cf < 8; ++cf) {
                bf16x8 b = ldfrag(Bs + (cf * 16 + l15) * 32 + sw8);
                acc[0][cf] = __builtin_amdgcn_mfma_f32_16x16x32_bf16(a0, b, acc[0][cf], 0, 0, 0);
                acc[1][cf] = __builtin_amdgcn_mfma_f32_16x16x32_bf16(a1, b, acc[1][cf], 0, 0, 0);
            }
            __syncthreads();
        }
    }

    // ---- phase 2: att GEMM, K=1024, B tile 64 rows (s*32+j -> WA row s*1024+n0+j) ----
    f32x4 acc2[2][4];    // [row frag][s*2 + col half]
#pragma unroll
    for (int i = 0; i < 2; ++i)
#pragma unroll
        for (int j = 0; j < 4; ++j) acc2[i][j] = z;
    {
        const unsigned short* aG0 = ATTb + (row0 + ar) * 1024 + kp_sw * 8;
        const unsigned short* aG1 = aG0 + 64 * 1024;
        const unsigned short* bG0 = WA + ((ar >> 5) * 1024 + n0 + (ar & 31)) * 1024 + kp_sw * 8;
        for (int kt = 0; kt < 32; ++kt) {
            gld16(aG0, aL0); gld16(aG1, aL1);
            gld16(bG0, bL0);                       // B tile: 64x32 = 4KB, 1 chunk/thread
            aG0 += 32; aG1 += 32; bG0 += 32;
            __syncthreads();
            bf16x8 a0 = ldfrag(As + aoff0);
            bf16x8 a1 = ldfrag(As + aoff1);
#pragma unroll
            for (int cf = 0; cf < 4; ++cf) {
                bf16x8 b = ldfrag(Bs + (cf * 16 + l15) * 32 + sw8);
                acc2[0][cf] = __builtin_amdgcn_mfma_f32_16x16x32_bf16(a0, b, acc2[0][cf], 0, 0, 0);
                acc2[1][cf] = __builtin_amdgcn_mfma_f32_16x16x32_bf16(a1, b, acc2[1][cf], 0, 0, 0);
            }
            __syncthreads();
        }
    }

    // ---- epilogue: fully in-register LSTM cell ----
    const int Rbase = row0 + wave * 32 + quad * 4;
    const int CYOFF = 8192 * 1024;
#pragma unroll
    for (int rf = 0; rf < 2; ++rf)
#pragma unroll
        for (int jp = 0; jp < 2; ++jp) {
            int col = n0 + jp * 16 + l15;
            float bi  = bias4[col];
            float bff = bias4[1024 + col];
            float bg  = bias4[2048 + col];
            float bo  = bias4[3072 + col];
            float ba0 = bias_att[col];
            float ba1 = bias_att[1024 + col];
#pragma unroll
            for (int reg = 0; reg < 4; ++reg) {
                int R = Rbase + rf * 16 + reg;
                int off = R * 1024 + col;
                float ig = sigmoidf_(acc[rf][0 + jp][reg] + bi);
                float fg = sigmoidf_(acc[rf][2 + jp][reg] + bff);
                float gg = tanhf_(acc[rf][4 + jp][reg] + bg);
                float og = sigmoidf_(acc[rf][6 + jp][reg] + bo);
                float ia = sigmoidf_(acc2[rf][0 + jp][reg] + ba0);
                float ag = tanhf_(acc2[rf][2 + jp][reg] + ba1);
                float cyv = fg * cx[off] + ig * gg + ia * ag;
                float hyv = og * tanhf_(cyv);
                out[off] = hyv;
                out[CYOFF + off] = cyv;
            }
        }
}

// ---------------- launch ----------------
extern "C" void kernel_launch(void* const* d_in, const int* in_sizes, int n_in,
                              void* d_out, int out_size, void* d_ws, size_t ws_size,
                              hipStream_t stream) {
    const float* input = (const float*)d_in[0];
    const float* hx    = (const float*)d_in[1];
    const float* cx    = (const float*)d_in[2];
    const float* att   = (const float*)d_in[3];
    const float* w_ih  = (const float*)d_in[4];
    const float* w_hh  = (const float*)d_in[5];
    const float* b_ih  = (const float*)d_in[6];
    const float* b_hh  = (const float*)d_in[7];
    const float* w_att = (const float*)d_in[8];
    const float* b_att = (const float*)d_in[9];
    float* out = (float*)d_out;

    char* ws = (char*)d_ws;
    unsigned short* XH   = (unsigned short*)(ws);                    // 8192x2048 bf16 (32MB)
    unsigned short* ATTb = (unsigned short*)(ws + 33554432);         // 8192x1024 bf16 (16MB)
    unsigned short* W4   = (unsigned short*)(ws + 50331648);         // 4096x2048 bf16 (16MB)
    unsigned short* WA   = (unsigned short*)(ws + 67108864);         // 2048x1024 bf16 (4MB)
    float* bias4         = (float*)(ws + 71303168);                  // 4096 f32

    cast_all_k<<<8704, 256, 0, stream>>>(input, hx, att, w_ih, w_hh, w_att,
                                         b_ih, b_hh, XH, ATTb, W4, WA, bias4);
    fused_gemm_k<<<dim3(64, 32), 256, 0, stream>>>(XH, W4, ATTb, WA, bias4, b_att, cx, out);
}

// Round 4
// 404.077 us; speedup vs baseline: 1.0857x; 1.0857x over previous
//
#include <hip/hip_runtime.h>

// LSTMCell with attention, MI355X gfx950.
// Round 4: (1) att phase FIRST, collapsed to attp (16 regs) before gates phase
//   -> peak accumulator pressure 80 not 96 -> 3 waves/SIMD (launch_bounds 256,3).
// (2) BK=64 K-loop (32KB LDS): half the barriers, 32 MFMA per barrier.
//   XOR swizzle chunk = kpos ^ (row&7) keeps ds_read_b128 conflict-free.

typedef __attribute__((ext_vector_type(8))) __bf16 bf16x8;
typedef __attribute__((ext_vector_type(8))) unsigned short ushort8;
typedef __attribute__((ext_vector_type(4))) float f32x4;

#define AS1 __attribute__((address_space(1)))
#define AS3 __attribute__((address_space(3)))

__device__ __forceinline__ void gld16(const unsigned short* g, unsigned short* l) {
    __builtin_amdgcn_global_load_lds((const AS1 void*)g, (AS3 void*)l, 16, 0, 0);
}

__device__ __forceinline__ unsigned short f2bf(float f) {
    unsigned int u = __builtin_bit_cast(unsigned int, f);
    u += 0x7fffu + ((u >> 16) & 1u);   // RNE
    return (unsigned short)(u >> 16);
}

__device__ __forceinline__ float sigmoidf_(float x) { return 1.f / (1.f + __expf(-x)); }
__device__ __forceinline__ float tanhf_(float x) {
    float e = __expf(-2.f * fabsf(x));
    float t = (1.f - e) / (1.f + e);
    return x >= 0.f ? t : -t;
}

__device__ __forceinline__ bf16x8 ldfrag(const unsigned short* p) {
    return __builtin_bit_cast(bf16x8, *(const ushort8*)p);
}

// ---------------- fused cast/pack + bias kernel (BW-bound, ~33us) ----------------
__global__ void cast_all_k(const float* __restrict__ input, const float* __restrict__ hx,
                           const float* __restrict__ att,   const float* __restrict__ w_ih,
                           const float* __restrict__ w_hh,  const float* __restrict__ w_att,
                           const float* __restrict__ b_ih,  const float* __restrict__ b_hh,
                           unsigned short* __restrict__ XH, unsigned short* __restrict__ ATTb,
                           unsigned short* __restrict__ W4, unsigned short* __restrict__ WA,
                           float* __restrict__ bias4)
{
    int gid = blockIdx.x * blockDim.x + threadIdx.x;
    if (gid < 4096) bias4[gid] = b_ih[gid] + b_hh[gid];
    const int total = 4456448;  // total float8 units
    for (int i = gid; i < total; i += gridDim.x * blockDim.x) {
        const float* src; unsigned short* dst; int ld, off, rel;
        if (i < 1048576)      { src = input; dst = XH;   ld = 2048; off = 0;    rel = i; }
        else if (i < 2097152) { src = hx;    dst = XH;   ld = 2048; off = 1024; rel = i - 1048576; }
        else if (i < 3145728) { src = att;   dst = ATTb; ld = 1024; off = 0;    rel = i - 2097152; }
        else if (i < 3670016) { src = w_ih;  dst = W4;   ld = 2048; off = 0;    rel = i - 3145728; }
        else if (i < 4194304) { src = w_hh;  dst = W4;   ld = 2048; off = 1024; rel = i - 3670016; }
        else                  { src = w_att; dst = WA;   ld = 1024; off = 0;    rel = i - 4194304; }
        int e = rel * 8;
        int r = e >> 10, c = e & 1023;   // all sources have 1024 fp32 cols
        const float4 v0 = *(const float4*)(src + e);
        const float4 v1 = *(const float4*)(src + e + 4);
        ushort8 p;
        p[0] = f2bf(v0.x); p[1] = f2bf(v0.y); p[2] = f2bf(v0.z); p[3] = f2bf(v0.w);
        p[4] = f2bf(v1.x); p[5] = f2bf(v1.y); p[6] = f2bf(v1.z); p[7] = f2bf(v1.w);
        *(ushort8*)(dst + r * ld + off + c) = p;
    }
}

// ---------------- fused GEMM + full LSTM epilogue ----------------
// Block (bx,by): rows row0..row0+127, H-cols n0..n0+31.
// Phase A (first): att_gates = ATTb[8192x1024] @ WA^T slices -> attp in regs.
// Phase B: gates = XH[8192x2048] @ W4^T (tile rows = gate*32+j).
// LDS layout: tile chunk L (16B) holds global k-chunk c=(L&7)^((L>>3)&7) of
// row L>>3  ->  fragment read for k-step s: row*64 + ((s*4+quad)^(row&7))*8.
__global__ __launch_bounds__(256, 3) void fused_gemm_k(
    const unsigned short* __restrict__ XH, const unsigned short* __restrict__ W4,
    const unsigned short* __restrict__ ATTb, const unsigned short* __restrict__ WA,
    const float* __restrict__ bias4, const float* __restrict__ bias_att,
    const float* __restrict__ cx, float* __restrict__ out)
{
    __shared__ unsigned short As[128 * 64];   // 16KB
    __shared__ unsigned short Bs[128 * 64];   // 16KB
    const int tid  = threadIdx.x;
    const int wave = tid >> 6, lane = tid & 63;
    const int l15 = lane & 15, quad = lane >> 4;
    const int row0 = blockIdx.x * 128;   // 64 blocks
    const int n0   = blockIdx.y * 32;    // 32 blocks

    // staging geometry: thread stages LDS chunks tid + p*256
    int r_[4], c_[4];
#pragma unroll
    for (int p = 0; p < 4; ++p) {
        int L = tid + p * 256;
        r_[p] = L >> 3;
        c_[p] = ((L & 7) ^ (r_[p] & 7)) * 8;
    }
    unsigned short* aL[4]; unsigned short* bL[4];
#pragma unroll
    for (int p = 0; p < 4; ++p) {
        aL[p] = As + (tid + p * 256) * 8;
        bL[p] = Bs + (tid + p * 256) * 8;
    }

    // fragment swizzle offsets (lane-constant)
    const int swz[2] = { ((quad) ^ (l15 & 7)) * 8, ((4 + quad) ^ (l15 & 7)) * 8 };
    const int arow0 = (wave * 32 + l15) * 64;

    const f32x4 z = {0.f, 0.f, 0.f, 0.f};

    // ---- phase A: att GEMM, K=1024 (16 iters of BK=64) ----
    f32x4 acc2[2][4];
#pragma unroll
    for (int i = 0; i < 2; ++i)
#pragma unroll
        for (int j = 0; j < 4; ++j) acc2[i][j] = z;
    {
        const unsigned short* aG[4]; const unsigned short* bG[2];
#pragma unroll
        for (int p = 0; p < 4; ++p) aG[p] = ATTb + (row0 + r_[p]) * 1024 + c_[p];
#pragma unroll
        for (int p = 0; p < 2; ++p) {
            int w = (r_[p] >> 5) * 1024 + n0 + (r_[p] & 31);   // slice*1024 + col
            bG[p] = WA + w * 1024 + c_[p];
        }
        for (int kt = 0; kt < 16; ++kt) {
#pragma unroll
            for (int p = 0; p < 4; ++p) { gld16(aG[p], aL[p]); aG[p] += 64; }
#pragma unroll
            for (int p = 0; p < 2; ++p) { gld16(bG[p], bL[p]); bG[p] += 64; }
            __syncthreads();
#pragma unroll
            for (int s = 0; s < 2; ++s) {
                bf16x8 a0 = ldfrag(As + arow0 + swz[s]);
                bf16x8 a1 = ldfrag(As + arow0 + 16 * 64 + swz[s]);
#pragma unroll
                for (int cf = 0; cf < 4; ++cf) {
                    bf16x8 b = ldfrag(Bs + (cf * 16 + l15) * 64 + swz[s]);
                    acc2[0][cf] = __builtin_amdgcn_mfma_f32_16x16x32_bf16(a0, b, acc2[0][cf], 0, 0, 0);
                    acc2[1][cf] = __builtin_amdgcn_mfma_f32_16x16x32_bf16(a1, b, acc2[1][cf], 0, 0, 0);
                }
            }
            __syncthreads();
        }
    }

    // collapse att accumulators -> attp (frees 16 regs before gates phase)
    f32x4 attp[2][2];
#pragma unroll
    for (int jp = 0; jp < 2; ++jp) {
        int col = n0 + jp * 16 + l15;
        float ba0 = bias_att[col], ba1 = bias_att[1024 + col];
#pragma unroll
        for (int rf = 0; rf < 2; ++rf)
#pragma unroll
            for (int reg = 0; reg < 4; ++reg)
                attp[rf][jp][reg] = sigmoidf_(acc2[rf][jp][reg] + ba0) *
                                    tanhf_(acc2[rf][2 + jp][reg] + ba1);
    }

    // ---- phase B: gates GEMM, K=2048 (32 iters of BK=64) ----
    f32x4 acc[2][8];
#pragma unroll
    for (int i = 0; i < 2; ++i)
#pragma unroll
        for (int j = 0; j < 8; ++j) acc[i][j] = z;
    {
        const unsigned short* aG[4]; const unsigned short* bG[4];
#pragma unroll
        for (int p = 0; p < 4; ++p) {
            aG[p] = XH + (row0 + r_[p]) * 2048 + c_[p];
            int w = (r_[p] >> 5) * 1024 + n0 + (r_[p] & 31);   // gate*1024 + col
            bG[p] = W4 + w * 2048 + c_[p];
        }
        for (int kt = 0; kt < 32; ++kt) {
#pragma unroll
            for (int p = 0; p < 4; ++p) { gld16(aG[p], aL[p]); aG[p] += 64; }
#pragma unroll
            for (int p = 0; p < 4; ++p) { gld16(bG[p], bL[p]); bG[p] += 64; }
            __syncthreads();
#pragma unroll
            for (int s = 0; s < 2; ++s) {
                bf16x8 a0 = ldfrag(As + arow0 + swz[s]);
                bf16x8 a1 = ldfrag(As + arow0 + 16 * 64 + swz[s]);
#pragma unroll
                for (int cf = 0; cf < 8; ++cf) {
                    bf16x8 b = ldfrag(Bs + (cf * 16 + l15) * 64 + swz[s]);
                    acc[0][cf] = __builtin_amdgcn_mfma_f32_16x16x32_bf16(a0, b, acc[0][cf], 0, 0, 0);
                    acc[1][cf] = __builtin_amdgcn_mfma_f32_16x16x32_bf16(a1, b, acc[1][cf], 0, 0, 0);
                }
            }
            __syncthreads();
        }
    }

    // ---- epilogue: fully in-register LSTM cell ----
    const int Rbase = row0 + wave * 32 + quad * 4;
    const int CYOFF = 8192 * 1024;
#pragma unroll
    for (int rf = 0; rf < 2; ++rf)
#pragma unroll
        for (int jp = 0; jp < 2; ++jp) {
            int col = n0 + jp * 16 + l15;
            float bi  = bias4[col];
            float bff = bias4[1024 + col];
            float bg  = bias4[2048 + col];
            float bo  = bias4[3072 + col];
#pragma unroll
            for (int reg = 0; reg < 4; ++reg) {
                int R = Rbase + rf * 16 + reg;
                int off = R * 1024 + col;
                float ig = sigmoidf_(acc[rf][0 + jp][reg] + bi);
                float fg = sigmoidf_(acc[rf][2 + jp][reg] + bff);
                float gg = tanhf_(acc[rf][4 + jp][reg] + bg);
                float og = sigmoidf_(acc[rf][6 + jp][reg] + bo);
                float cyv = fg * cx[off] + ig * gg + attp[rf][jp][reg];
                float hyv = og * tanhf_(cyv);
                out[off] = hyv;
                out[CYOFF + off] = cyv;
            }
        }
}

// ---------------- launch ----------------
extern "C" void kernel_launch(void* const* d_in, const int* in_sizes, int n_in,
                              void* d_out, int out_size, void* d_ws, size_t ws_size,
                              hipStream_t stream) {
    const float* input = (const float*)d_in[0];
    const float* hx    = (const float*)d_in[1];
    const float* cx    = (const float*)d_in[2];
    const float* att   = (const float*)d_in[3];
    const float* w_ih  = (const float*)d_in[4];
    const float* w_hh  = (const float*)d_in[5];
    const float* b_ih  = (const float*)d_in[6];
    const float* b_hh  = (const float*)d_in[7];
    const float* w_att = (const float*)d_in[8];
    const float* b_att = (const float*)d_in[9];
    float* out = (float*)d_out;

    char* ws = (char*)d_ws;
    unsigned short* XH   = (unsigned short*)(ws);                    // 8192x2048 bf16 (32MB)
    unsigned short* ATTb = (unsigned short*)(ws + 33554432);         // 8192x1024 bf16 (16MB)
    unsigned short* W4   = (unsigned short*)(ws + 50331648);         // 4096x2048 bf16 (16MB)
    unsigned short* WA   = (unsigned short*)(ws + 67108864);         // 2048x1024 bf16 (4MB)
    float* bias4         = (float*)(ws + 71303168);                  // 4096 f32

    cast_all_k<<<8704, 256, 0, stream>>>(input, hx, att, w_ih, w_hh, w_att,
                                         b_ih, b_hh, XH, ATTb, W4, WA, bias4);
    fused_gemm_k<<<dim3(64, 32), 256, 0, stream>>>(XH, W4, ATTb, WA, bias4, b_att, cx, out);
}